// Round 1
// baseline (148.027 us; speedup 1.0000x reference)
//
#include <hip/hip_runtime.h>
#include <math.h>

#define HH 512
#define WW 512
#define PHH 16
#define PWW 16
#define QQ 3
#define NHH 32
#define NWW 32
#define PP 1024
#define BB 64

// Twiddles: TW[j] = exp(-2*pi*i*j/16), j = 0..7
__device__ __constant__ float TWC[8] = {
    1.0f,  0.92387953251f,  0.70710678119f,  0.38268343236f,
    0.0f, -0.38268343236f, -0.70710678119f, -0.92387953251f};
__device__ __constant__ float TWS[8] = {
    0.0f, -0.38268343236f, -0.70710678119f, -0.92387953251f,
   -1.0f, -0.92387953251f, -0.70710678119f, -0.38268343236f};

// Fully-unrolled in-register 16-point complex FFT (radix-2 DIT).
// SGN=+1: forward (exp(-i)); SGN=-1: unscaled inverse (exp(+i)).
template <int SGN>
__device__ __forceinline__ void fft16(float* re, float* im) {
  // bit-reversal permutation for n=16
#define SWAP_(a, b)                              \
  { float t = re[a]; re[a] = re[b]; re[b] = t;   \
    t = im[a]; im[a] = im[b]; im[b] = t; }
  SWAP_(1, 8) SWAP_(2, 4) SWAP_(3, 12) SWAP_(5, 10) SWAP_(7, 14) SWAP_(11, 13)
#undef SWAP_
#pragma unroll
  for (int len = 2; len <= 16; len <<= 1) {
    const int half = len >> 1;
    const int tstep = 16 / len;
#pragma unroll
    for (int i = 0; i < 16; i += len) {
#pragma unroll
      for (int j = 0; j < half; ++j) {
        const float wr = TWC[j * tstep];
        const float wi = (SGN > 0) ? TWS[j * tstep] : -TWS[j * tstep];
        const int a = i + j;
        const int c = i + j + half;
        const float tr = re[c] * wr - im[c] * wi;
        const float ti = re[c] * wi + im[c] * wr;
        re[c] = re[a] - tr;
        im[c] = im[a] - ti;
        re[a] = re[a] + tr;
        im[a] = im[a] + ti;
      }
    }
  }
}

// Block: 256 threads = 16 groups x 16 threads.
// Block handles one patch p and 16 batch indices; group g -> batch b0+g,
// thread r within group -> row r of the 16x16 patch.
__global__ __launch_bounds__(256) void psm_kernel(
    const float* __restrict__ x, const float* __restrict__ logits,
    const float* __restrict__ mu, const float* __restrict__ sigma,
    const float* __restrict__ bias, float* __restrict__ out) {
  __shared__ float S_lds[256];
  __shared__ float t_re[16 * 272];  // 16 groups, 16 rows, stride 17
  __shared__ float t_im[16 * 272];

  const int tid = threadIdx.x;
  const int p = blockIdx.x >> 2;
  const int b0 = (blockIdx.x & 3) << 4;
  const int g = tid >> 4;
  const int r = tid & 15;
  const int b = b0 + g;
  const int nh = p >> 5;
  const int nw = p & 31;

  // ---- Phase A: spectral filter S for this patch into LDS ----
  {
    const int fy_i = tid >> 4;
    const int fx_i = tid & 15;
    const float fy = (float)(fy_i < 8 ? fy_i : fy_i - 16) * (1.0f / 16.0f);
    const float fx = (float)(fx_i < 8 ? fx_i : fx_i - 16) * (1.0f / 16.0f);
    const float l0 = logits[p * QQ + 0];
    const float l1 = logits[p * QQ + 1];
    const float l2 = logits[p * QQ + 2];
    const float lm = fmaxf(l0, fmaxf(l1, l2));
    const float e0 = __expf(l0 - lm);
    const float e1 = __expf(l1 - lm);
    const float e2 = __expf(l2 - lm);
    const float inv = 1.0f / (e0 + e1 + e2);
    const float wq[3] = {e0 * inv, e1 * inv, e2 * inv};
    float s = 0.0f;
#pragma unroll
    for (int q = 0; q < QQ; ++q) {
      const float muy = mu[(p * QQ + q) * 2 + 0];
      const float mux = mu[(p * QQ + q) * 2 + 1];
      const float isy = 1.0f / sigma[(p * QQ + q) * 2 + 0];
      const float isx = 1.0f / sigma[(p * QQ + q) * 2 + 1];
      const float dy1 = (fy - muy) * isy;
      const float dx1 = (fx - mux) * isx;
      const float dy2 = (fy + muy) * isy;
      const float dx2 = (fx + mux) * isx;
      const float g1 = __expf(-0.5f * (dy1 * dy1 + dx1 * dx1));
      const float g2 = __expf(-0.5f * (dy2 * dy2 + dx2 * dx2));
      s += wq[q] * (g1 + g2);
    }
    // fold jitter and the ifft2 1/256 normalization into S
    S_lds[tid] = (s + 1e-6f) * (1.0f / 256.0f);
  }
  __syncthreads();

  // ---- Phase B: load row r of this (p,b) patch; forward row FFT ----
  const size_t rowoff =
      (size_t)b * (HH * WW) + (size_t)(nh * PHH + r) * WW + (size_t)(nw * PWW);
  const float* xrow = x + rowoff;
  float re[16], im[16];
#pragma unroll
  for (int c4 = 0; c4 < 4; ++c4) {
    const float4 v = ((const float4*)xrow)[c4];
    re[c4 * 4 + 0] = v.x;
    re[c4 * 4 + 1] = v.y;
    re[c4 * 4 + 2] = v.z;
    re[c4 * 4 + 3] = v.w;
  }
#pragma unroll
  for (int c = 0; c < 16; ++c) im[c] = 0.0f;

  fft16<1>(re, im);

  // ---- Phase C: transpose via LDS (row write, column read) ----
  float* mre = &t_re[g * 272];
  float* mim = &t_im[g * 272];
#pragma unroll
  for (int c = 0; c < 16; ++c) {
    mre[r * 17 + c] = re[c];
    mim[r * 17 + c] = im[c];
  }
  __syncthreads();
#pragma unroll
  for (int k = 0; k < 16; ++k) {
    re[k] = mre[k * 17 + r];
    im[k] = mim[k * 17 + r];
  }
  __syncthreads();

  // ---- Phase D: column FFT, multiply by S, inverse column FFT ----
  fft16<1>(re, im);
#pragma unroll
  for (int k = 0; k < 16; ++k) {
    const float s = S_lds[k * 16 + r];
    re[k] *= s;
    im[k] *= s;
  }
  fft16<-1>(re, im);

  // ---- Phase E: transpose back (column write, row read) ----
#pragma unroll
  for (int k = 0; k < 16; ++k) {
    mre[k * 17 + r] = re[k];
    mim[k * 17 + r] = im[k];
  }
  __syncthreads();
#pragma unroll
  for (int c = 0; c < 16; ++c) {
    re[c] = mre[r * 17 + c];
    im[c] = mim[r * 17 + c];
  }

  // ---- Phase F: inverse row FFT, take real part, add bias, store ----
  fft16<-1>(re, im);

  const float* brow = bias + (size_t)p * 256 + (size_t)r * 16;
  float* orow = out + rowoff;
#pragma unroll
  for (int c4 = 0; c4 < 4; ++c4) {
    const float4 bv = ((const float4*)brow)[c4];
    float4 o;
    o.x = re[c4 * 4 + 0] + bv.x;
    o.y = re[c4 * 4 + 1] + bv.y;
    o.z = re[c4 * 4 + 2] + bv.z;
    o.w = re[c4 * 4 + 3] + bv.w;
    ((float4*)orow)[c4] = o;
  }
}

extern "C" void kernel_launch(void* const* d_in, const int* in_sizes, int n_in,
                              void* d_out, int out_size, void* d_ws,
                              size_t ws_size, hipStream_t stream) {
  (void)in_sizes;
  (void)n_in;
  (void)out_size;
  (void)d_ws;
  (void)ws_size;
  const float* x = (const float*)d_in[0];
  const float* logits = (const float*)d_in[1];
  const float* mu = (const float*)d_in[2];
  const float* sigma = (const float*)d_in[3];
  const float* bias = (const float*)d_in[4];
  float* out = (float*)d_out;

  // 1024 patches x 4 batch-chunks of 16
  psm_kernel<<<dim3(PP * 4), dim3(256), 0, stream>>>(x, logits, mu, sigma,
                                                     bias, out);
}